// Round 14
// baseline (1421.650 us; speedup 1.0000x reference)
//
#include <hip/hip_runtime.h>
#include <hip/hip_bf16.h>
#include <math.h>

typedef __hip_bfloat16 bf16;
typedef __attribute__((ext_vector_type(8))) short bf16x8;   // 8 bf16 = 4 VGPR
typedef __attribute__((ext_vector_type(4))) float f32x4;    // MFMA acc

#define BATCH   16
#define SEQLEN  2048
#define INDIM   64
#define HIDD    256
#define STATE_D 256
#define MLPD    1024
#define OUTD    128
#define NLAYERS 4
#define M_TOK   (BATCH*SEQLEN)     // 32768 tokens
#define CHUNK   64
#define NCHUNK  (SEQLEN/CHUNK)     // 32 chunks per batch

// ---- fp32 masters (residual chain precision) -------------------------------
__device__ float g_h [(size_t)M_TOK*256];
__device__ float g_y [(size_t)M_TOK*256];
__device__ float g_bu[(size_t)M_TOK*512];
__device__ float g_carry[512*512];
// ---- bf16 shadows / packed weights (MFMA operands) -------------------------
__device__ bf16  g_hb [(size_t)M_TOK*256];
__device__ bf16  g_yb [(size_t)M_TOK*256];
__device__ bf16  g_bub[(size_t)M_TOK*512];
__device__ bf16  g_zb [(size_t)M_TOK*1024];
__device__ bf16  g_Bnb[512*256];    // B_norm: rows 0-255 re, 256-511 im
__device__ bf16  g_Cwb[256*512];    // [Cre | -Cim]
__device__ bf16  g_Whb[1024*256];   // layer-local Wh
__device__ bf16  g_Wob[256*1024];   // layer-local Wo

#define SF_H  0
#define SF_Y  1
#define SF_BU 2
#define SB_HB  0
#define SB_YB  1
#define SB_BUB 2
#define SB_ZB  3
#define SB_BNB 4
#define SB_CWB 5
#define SB_WHB 6
#define SB_WOB 7

__device__ __forceinline__ float* buff(int sel){
  switch(sel){ case SF_H: return g_h; case SF_Y: return g_y; default: return g_bu; }
}
__device__ __forceinline__ bf16* bufb(int sel){
  switch(sel){
    case SB_HB:  return g_hb;  case SB_YB:  return g_yb;
    case SB_BUB: return g_bub; case SB_ZB:  return g_zb;
    case SB_BNB: return g_Bnb; case SB_CWB: return g_Cwb;
    case SB_WHB: return g_Whb; default:     return g_Wob; }
}

// async global->LDS, 16B per lane; lds base must be wave-uniform
__device__ __forceinline__ void gload_lds16(const void* g, void* l){
  __builtin_amdgcn_global_load_lds(
      (const __attribute__((address_space(1))) void*)g,
      (__attribute__((address_space(3))) void*)l, 16, 0, 0);
}

// ---------------------------------------------------------------------------
// MFMA GEMM: C[M,N] = act(A @ W^T + bias) (+res / +dscale*res)
// A: bf16 [M,K] lda;  W: bf16 [N,K] ldw.  128x128 block, 4 waves, BK=32.
// Unpadded LDS rows (32 shorts), XOR-4 16B-group swizzle: phys = logic^(row&3)
//  -> ds_read_b128 lands 8 lanes on each 16B bank-group = zero conflict.
// Staging via global_load_lds (wave-uniform LDS base + lane*16B, contiguous),
// swizzle applied on the per-lane GLOBAL source column.
// ---------------------------------------------------------------------------
template<int ACT, int FLAGS>
__global__ __launch_bounds__(256) void mfma_gemm(
    int aSel, int lda, int wSel, int ldw,
    int oFSel, int oBSel, int ldc,
    const float* __restrict__ bias,
    int rSel, int ldres,
    const float* __restrict__ dscale,
    int K)
{
  const bf16* A = bufb(aSel);
  const bf16* W = bufb(wSel);
  float* OF = (oFSel >= 0) ? buff(oFSel) : nullptr;
  bf16*  OB = (oBSel >= 0) ? bufb(oBSel) : nullptr;
  const float* res = (rSel >= 0) ? buff(rSel) : nullptr;

  __shared__ __align__(16) unsigned short As[128*32];
  __shared__ __align__(16) unsigned short Ws[128*32];

  const int tid  = threadIdx.x;
  const int row0 = blockIdx.y * 128, col0 = blockIdx.x * 128;
  const int lane = tid & 63;
  const int m16  = lane & 15, quad = lane >> 4;
  const int wv   = tid >> 6;
  const int wm   = (wv & 1) * 64, wn = (wv >> 1) * 64;
  // staging: wave wv covers tile rows [32*wv, 32*wv+32), two 16-row calls
  const int sj   = lane >> 2;          // row within 16-row group
  const int sp   = lane & 3;           // physical 16B group
  const int sg   = sp ^ (sj & 3);      // logical 16B group (swizzle)
  const int pg   = quad ^ (m16 & 3);   // read-side physical group

  f32x4 acc[4][4] = {};

  for (int k0 = 0; k0 < K; k0 += 32){
    #pragma unroll
    for (int q = 0; q < 2; q++){
      const int r = 32*wv + 16*q + sj;
      gload_lds16(&A[(size_t)(row0 + r)*lda + k0 + sg*8], &As[(32*wv + 16*q)*32]);
      gload_lds16(&W[(size_t)(col0 + r)*ldw + k0 + sg*8], &Ws[(32*wv + 16*q)*32]);
    }
    __syncthreads();

    bf16x8 af[4], wf[4];
    #pragma unroll
    for (int i = 0; i < 4; i++){
      af[i] = *reinterpret_cast<const bf16x8*>(&As[(wm + 16*i + m16)*32 + pg*8]);
      wf[i] = *reinterpret_cast<const bf16x8*>(&Ws[(wn + 16*i + m16)*32 + pg*8]);
    }
    #pragma unroll
    for (int i = 0; i < 4; i++)
      #pragma unroll
      for (int j = 0; j < 4; j++)
        acc[i][j] = __builtin_amdgcn_mfma_f32_16x16x32_bf16(af[i], wf[j], acc[i][j], 0, 0, 0);
    __syncthreads();
  }

  // epilogue: C/D layout col=lane&15, row=quad*4+reg
  #pragma unroll
  for (int i = 0; i < 4; i++){
    #pragma unroll
    for (int j = 0; j < 4; j++){
      const int col = col0 + wn + 16*j + m16;
      #pragma unroll
      for (int r = 0; r < 4; r++){
        const int row = row0 + wm + 16*i + quad*4 + r;
        float v = acc[i][j][r];
        if (FLAGS & 1) v += bias[col];
        if (ACT == 1)  v = 0.5f * v * (1.0f + erff(v * 0.70710678118654752f));
        if (FLAGS & 2) v += res[(size_t)row*ldres + col];
        if (FLAGS & 4) v += dscale[col] * res[(size_t)row*ldres + col];
        const size_t o = (size_t)row*ldc + col;
        if (OF) OF[o] = v;
        if (OB) OB[o] = __float2bfloat16(v);
      }
    }
  }
}

// ---------------------------------------------------------------------------
// fp32 tiled GEMMs for the small ends (embed, out).
// ---------------------------------------------------------------------------
__global__ __launch_bounds__(256) void emb_gemm(
    const float* __restrict__ x, const float* __restrict__ W,
    const float* __restrict__ b)
{
  __shared__ __align__(16) float Asx[16][68];
  __shared__ __align__(16) float Wsx[16][68];
  const int tid = threadIdx.x;
  const int tx = tid & 15, ty = tid >> 4;
  const int row0 = blockIdx.y * 64, col0 = blockIdx.x * 64;
  const int lc = tid & 15, lr = tid >> 4;
  float acc[4][4] = {};
  for (int k0 = 0; k0 < INDIM; k0 += 16){
    #pragma unroll
    for (int i = 0; i < 4; i++){
      Asx[lc][lr + 16*i] = x[(size_t)(row0 + lr + 16*i)*INDIM + k0 + lc];
      Wsx[lc][lr + 16*i] = W[(size_t)(col0 + lr + 16*i)*INDIM + k0 + lc];
    }
    __syncthreads();
    #pragma unroll
    for (int k = 0; k < 16; k++){
      float4 av = *reinterpret_cast<const float4*>(&Asx[k][ty*4]);
      float4 bv = *reinterpret_cast<const float4*>(&Wsx[k][tx*4]);
      float a[4] = {av.x, av.y, av.z, av.w};
      float b2[4] = {bv.x, bv.y, bv.z, bv.w};
      #pragma unroll
      for (int i = 0; i < 4; i++)
        #pragma unroll
        for (int j = 0; j < 4; j++)
          acc[i][j] = fmaf(a[i], b2[j], acc[i][j]);
    }
    __syncthreads();
  }
  #pragma unroll
  for (int i = 0; i < 4; i++){
    const int r = row0 + ty*4 + i;
    #pragma unroll
    for (int j = 0; j < 4; j++){
      const int cn = col0 + tx*4 + j;
      float v = acc[i][j] + b[cn];
      g_h [(size_t)r*HIDD + cn] = v;
      g_hb[(size_t)r*HIDD + cn] = __float2bfloat16(v);
    }
  }
}

__global__ __launch_bounds__(256) void out_gemm(
    const float* __restrict__ W, const float* __restrict__ b,
    float* __restrict__ out)
{
  __shared__ __align__(16) float Asx[16][68];
  __shared__ __align__(16) float Wsx[16][68];
  const int tid = threadIdx.x;
  const int tx = tid & 15, ty = tid >> 4;
  const int row0 = blockIdx.y * 64, col0 = blockIdx.x * 64;
  const int lc = tid & 15, lr = tid >> 4;
  float acc[4][4] = {};
  for (int k0 = 0; k0 < HIDD; k0 += 16){
    #pragma unroll
    for (int i = 0; i < 4; i++){
      Asx[lc][lr + 16*i] = g_h[(size_t)(row0 + lr + 16*i)*HIDD + k0 + lc];
      Wsx[lc][lr + 16*i] = W[(size_t)(col0 + lr + 16*i)*HIDD + k0 + lc];
    }
    __syncthreads();
    #pragma unroll
    for (int k = 0; k < 16; k++){
      float4 av = *reinterpret_cast<const float4*>(&Asx[k][ty*4]);
      float4 bv = *reinterpret_cast<const float4*>(&Wsx[k][tx*4]);
      float a[4] = {av.x, av.y, av.z, av.w};
      float b2[4] = {bv.x, bv.y, bv.z, bv.w};
      #pragma unroll
      for (int i = 0; i < 4; i++)
        #pragma unroll
        for (int j = 0; j < 4; j++)
          acc[i][j] = fmaf(a[i], b2[j], acc[i][j]);
    }
    __syncthreads();
  }
  #pragma unroll
  for (int i = 0; i < 4; i++){
    const int r = row0 + ty*4 + i;
    #pragma unroll
    for (int j = 0; j < 4; j++){
      const int cn = col0 + tx*4 + j;
      out[(size_t)r*OUTD + cn] = acc[i][j] + b[cn];
    }
  }
}

// ---------------------------------------------------------------------------
// lam_s = exp(-exp(nu)) * (cos(exp(th)) + i sin(exp(th)))
// ---------------------------------------------------------------------------
__device__ __forceinline__ void lam_of(const float* __restrict__ nu_log,
                                       const float* __restrict__ th_log,
                                       int s, float& lr, float& li)
{
  float nu  = expf(nu_log[s]);
  float th  = expf(th_log[s]);
  float mag = expf(-nu);
  lr = mag * cosf(th);
  li = mag * sinf(th);
}

// Local inclusive scan over 64-token chunks (fp32); chunk carry out.
__global__ __launch_bounds__(256) void scan_local(
    const float* __restrict__ nu_log, const float* __restrict__ th_log)
{
  const int blk = blockIdx.x;          // chunk 0..511
  const int s   = threadIdx.x;
  float lr, li; lam_of(nu_log, th_log, s, lr, li);
  float ar = 0.f, ai = 0.f;
  size_t base = (size_t)blk * CHUNK * 512 + s;
  for (int t = 0; t < CHUNK; t++){
    float br = g_bu[base + (size_t)t*512];
    float bi = g_bu[base + (size_t)t*512 + 256];
    float nr = fmaf(lr, ar, fmaf(-li, ai, br));
    float ni = fmaf(lr, ai, fmaf( li, ar, bi));
    ar = nr; ai = ni;
    g_bu[base + (size_t)t*512]       = ar;
    g_bu[base + (size_t)t*512 + 256] = ai;
  }
  g_carry[(size_t)blk*512 + s]       = ar;
  g_carry[(size_t)blk*512 + 256 + s] = ai;
}

// Fixup + bf16 shadow emit. Writes ONLY the bf16 shadow (fp32 states are
// dead after this point — y-GEMM consumes g_bub). Saves 64 MB/layer.
__global__ __launch_bounds__(256) void scan_fix(
    const float* __restrict__ nu_log, const float* __restrict__ th_log)
{
  const int blk = blockIdx.x;
  const int c   = blk & (NCHUNK - 1);
  const int s   = threadIdx.x;
  float lr, li; lam_of(nu_log, th_log, s, lr, li);
  float cr = 0.f, ci = 0.f;
  if (c > 0){
    float Tr = lr, Ti = li;
    #pragma unroll
    for (int i = 0; i < 6; i++){ float nr = Tr*Tr - Ti*Ti; Ti = 2.f*Tr*Ti; Tr = nr; }
    const int bstart = blk - c;
    for (int j = 0; j < c; j++){
      float er = g_carry[(size_t)(bstart + j)*512 + s];
      float ei = g_carry[(size_t)(bstart + j)*512 + 256 + s];
      float nr = fmaf(Tr, cr, fmaf(-Ti, ci, er));
      float ni = fmaf(Tr, ci, fmaf( Ti, cr, ei));
      cr = nr; ci = ni;
    }
  }
  float pr = lr, pi = li;                    // lam^{t+1}
  size_t base = (size_t)blk * CHUNK * 512 + s;
  for (int t = 0; t < CHUNK; t++){
    size_t o = base + (size_t)t*512;
    float vr = g_bu[o], vi = g_bu[o + 256];
    if (c > 0){
      vr += pr*cr - pi*ci;
      vi += pr*ci + pi*cr;
      float nr = pr*lr - pi*li;
      pi = pr*li + pi*lr; pr = nr;
    }
    g_bub[o]       = __float2bfloat16(vr);
    g_bub[o + 256] = __float2bfloat16(vi);
  }
}

// Pack B_norm -> bf16 (512 x 256): re rows 0-255, im rows 256-511
__global__ __launch_bounds__(256) void pack_B(
    const float* __restrict__ Bre, const float* __restrict__ Bim,
    const float* __restrict__ gl)
{
  int idx = blockIdx.x * 256 + threadIdx.x;      // 0..65535
  int s = idx >> 8;
  float g = expf(gl[s]);
  g_Bnb[idx]         = __float2bfloat16(Bre[idx] * g);
  g_Bnb[65536 + idx] = __float2bfloat16(Bim[idx] * g);
}

// Pack Cw -> bf16 (256 x 512): [Cre | -Cim]
__global__ __launch_bounds__(256) void pack_C(
    const float* __restrict__ Cre, const float* __restrict__ Cim)
{
  int idx = blockIdx.x * 256 + threadIdx.x;      // 0..65535
  int h = idx >> 8, s = idx & 255;
  g_Cwb[(size_t)h*512 + s]       = __float2bfloat16( Cre[idx]);
  g_Cwb[(size_t)h*512 + 256 + s] = __float2bfloat16(-Cim[idx]);
}

// fp32 -> bf16 weight convert
__global__ __launch_bounds__(256) void conv_bf16(
    const float* __restrict__ src, int dstSel, int n)
{
  int i = blockIdx.x * 256 + threadIdx.x;
  if (i < n) bufb(dstSel)[i] = __float2bfloat16(src[i]);
}

// ---------------------------------------------------------------------------
extern "C" void kernel_launch(void* const* d_in, const int* in_sizes, int n_in,
                              void* d_out, int out_size, void* d_ws, size_t ws_size,
                              hipStream_t stream)
{
  (void)d_ws; (void)ws_size; (void)out_size; (void)n_in; (void)in_sizes;
  const float* x      = (const float*)d_in[0];
  const float* emb_W  = (const float*)d_in[1];
  const float* emb_b  = (const float*)d_in[2];
  const float* nu_log = (const float*)d_in[3];
  const float* th_log = (const float*)d_in[4];
  const float* ga_log = (const float*)d_in[5];
  const float* B_re   = (const float*)d_in[6];
  const float* B_im   = (const float*)d_in[7];
  const float* C_re   = (const float*)d_in[8];
  const float* C_im   = (const float*)d_in[9];
  const float* Dv     = (const float*)d_in[10];
  const float* Wh     = (const float*)d_in[11];
  const float* bh     = (const float*)d_in[12];
  const float* Wo     = (const float*)d_in[13];
  const float* bo     = (const float*)d_in[14];
  const float* out_W  = (const float*)d_in[15];
  const float* out_b  = (const float*)d_in[16];

  const dim3 blk(256);

  emb_gemm<<<dim3(HIDD/64, M_TOK/64), blk, 0, stream>>>(x, emb_W, emb_b);

  for (int l = 0; l < NLAYERS; l++){
    pack_B<<<dim3(256), blk, 0, stream>>>(B_re + (size_t)l*65536,
                                          B_im + (size_t)l*65536,
                                          ga_log + l*STATE_D);
    pack_C<<<dim3(256), blk, 0, stream>>>(C_re + (size_t)l*65536,
                                          C_im + (size_t)l*65536);
    conv_bf16<<<dim3(1024), blk, 0, stream>>>(Wh + (size_t)l*262144, SB_WHB, 262144);
    conv_bf16<<<dim3(1024), blk, 0, stream>>>(Wo + (size_t)l*262144, SB_WOB, 262144);

    // Bu = h @ Bn^T   (32768 x 512 x 256) -> g_bu fp32
    mfma_gemm<0, 0><<<dim3(4, M_TOK/128), blk, 0, stream>>>(
        SB_HB, HIDD, SB_BNB, HIDD, SF_BU, -1, 512,
        nullptr, -1, 0, nullptr, HIDD);

    scan_local<<<dim3(M_TOK/CHUNK), blk, 0, stream>>>(nu_log + l*STATE_D, th_log + l*STATE_D);
    scan_fix  <<<dim3(M_TOK/CHUNK), blk, 0, stream>>>(nu_log + l*STATE_D, th_log + l*STATE_D);

    // y = states @ Cw^T + D*h   (32768 x 256 x 512) -> g_y + g_yb
    mfma_gemm<0, 4><<<dim3(2, M_TOK/128), blk, 0, stream>>>(
        SB_BUB, 512, SB_CWB, 512, SF_Y, SB_YB, HIDD,
        nullptr, SF_H, HIDD, Dv + l*HIDD, 512);

    // z = gelu(y @ Wh^T + bh)   (32768 x 1024 x 256) -> g_zb only
    mfma_gemm<1, 1><<<dim3(8, M_TOK/128), blk, 0, stream>>>(
        SB_YB, HIDD, SB_WHB, STATE_D, -1, SB_ZB, MLPD,
        bh + l*MLPD, -1, 0, nullptr, STATE_D);

    // h = z @ Wo^T + bo + y     (32768 x 256 x 1024) -> g_h + g_hb
    mfma_gemm<0, 3><<<dim3(2, M_TOK/128), blk, 0, stream>>>(
        SB_ZB, MLPD, SB_WOB, MLPD, SF_H, SB_HB, HIDD,
        bo + l*HIDD, SF_Y, HIDD, nullptr, MLPD);
  }

  out_gemm<<<dim3(OUTD/64, M_TOK/64), blk, 0, stream>>>(out_W, out_b, (float*)d_out);
}